// Round 2
// baseline (931.394 us; speedup 1.0000x reference)
//
#include <hip/hip_runtime.h>
#include <hip/hip_bf16.h>

// Problem dims (fixed by setup_inputs)
constexpr int BQ = 32;          // batch
constexpr int TT = 128;         // tokens
constexpr int DD = 13;          // depth
constexpr int E  = 1024;        // d_emb
constexpr int P  = 64;          // n_parts
constexpr int C  = 16;          // d_cap
constexpr int NC = 5;           // n_classes
constexpr int NI = TT * DD;     // 1664 input capsules (routing 1)
constexpr int NROWS = BQ * NI;  // 53248
constexpr int RB = 16;          // rows per block in k1

// ---------------------------------------------------------------------------
// sumfa[b] = sum_i fa[b,i] = 13 * sum_t mask[b,t]   (fa = sigmoid(logit(m)) = m)
__global__ void k_sumfa(const float* __restrict__ mask, float* __restrict__ sumfa)
{
    const int b = blockIdx.x, tid = threadIdx.x;   // 128 threads
    float v = mask[b * TT + tid];
#pragma unroll
    for (int off = 32; off > 0; off >>= 1) v += __shfl_xor(v, off);
    __shared__ float p2[2];
    if ((tid & 63) == 0) p2[tid >> 6] = v;
    __syncthreads();
    if (tid == 0) sumfa[b] = (float)DD * (p2[0] + p2[1]);
}

// ---------------------------------------------------------------------------
// K1: LayerNorm -> Linear(1024->64) -> Swish -> V = mu @ W1 + B1.
// V stored as [row][h][j] (j innermost) so k2's lane=j reads coalesce.
// 16 rows per block, 256 threads (4 waves).
__global__ __launch_bounds__(256) void
k1_parts_v(const float* __restrict__ embs, const float* __restrict__ depth_emb,
           const float* __restrict__ ln_w, const float* __restrict__ ln_b,
           const float* __restrict__ dp_w, const float* __restrict__ dp_b,
           const float* __restrict__ W1,  const float* __restrict__ B1,
           float* __restrict__ V)
{
    __shared__ float xn[RB][E];    // 64 KB
    __shared__ float muL[RB][P];   // 4 KB
    const int tid = threadIdx.x;
    const int wave = tid >> 6, lane = tid & 63;
    const int row0 = blockIdx.x * RB;

    // Phase 1: LayerNorm. Each wave handles 4 rows (wave-local reductions only).
    for (int rr = 0; rr < 4; ++rr) {
        const int r = wave * 4 + rr;
        const int row = row0 + r;
        const int dd = row % DD;
        const float* xr = embs + (size_t)row * E;
        const float* de = depth_emb + (size_t)dd * E;
        float4 xv[4];
        float s = 0.f;
#pragma unroll
        for (int k = 0; k < 4; ++k) {
            const int e = 4 * lane + 256 * k;
            float4 a = *reinterpret_cast<const float4*>(xr + e);
            const float4 d4 = *reinterpret_cast<const float4*>(de + e);
            a.x += d4.x; a.y += d4.y; a.z += d4.z; a.w += d4.w;
            xv[k] = a;
            s += a.x + a.y + a.z + a.w;
        }
#pragma unroll
        for (int off = 32; off > 0; off >>= 1) s += __shfl_xor(s, off);
        const float mean = s * (1.f / E);
        float vs = 0.f;
#pragma unroll
        for (int k = 0; k < 4; ++k) {
            const float4 a = xv[k];
            const float dx = a.x - mean, dy = a.y - mean, dz = a.z - mean, dw = a.w - mean;
            vs += dx * dx + dy * dy + dz * dz + dw * dw;
        }
#pragma unroll
        for (int off = 32; off > 0; off >>= 1) vs += __shfl_xor(vs, off);
        const float rstd = rsqrtf(vs * (1.f / E) + 1e-5f);
#pragma unroll
        for (int k = 0; k < 4; ++k) {
            const int e = 4 * lane + 256 * k;
            const float4 a = xv[k];
            const float4 w4 = *reinterpret_cast<const float4*>(ln_w + e);
            const float4 b4 = *reinterpret_cast<const float4*>(ln_b + e);
            float4 o4;
            o4.x = (a.x - mean) * rstd * w4.x + b4.x;
            o4.y = (a.y - mean) * rstd * w4.y + b4.y;
            o4.z = (a.z - mean) * rstd * w4.z + b4.z;
            o4.w = (a.w - mean) * rstd * w4.w + b4.w;
            *reinterpret_cast<float4*>(&xn[r][e]) = o4;
        }
    }
    __syncthreads();

    // Phase 2: h = xn @ dp_w^T + dp_b ; mu = swish(h).
    // thread = (pg 0..15, eq 0..15); computes parts {pg, pg+16, pg+32, pg+48}
    // over interleaved K-slice eq (bank-conflict-free: stride 16B across eq).
    {
        const int pg = tid >> 4, eq = tid & 15;
        float acc[4][RB];
#pragma unroll
        for (int q = 0; q < 4; ++q)
#pragma unroll
            for (int r = 0; r < RB; ++r) acc[q][r] = 0.f;

        for (int kk = 0; kk < 16; ++kk) {
            const int e = kk * 64 + eq * 4;
            float4 w4[4];
#pragma unroll
            for (int q = 0; q < 4; ++q)
                w4[q] = *reinterpret_cast<const float4*>(dp_w + (size_t)(pg + q * 16) * E + e);
#pragma unroll
            for (int r = 0; r < RB; ++r) {
                const float4 x4 = *reinterpret_cast<const float4*>(&xn[r][e]);
#pragma unroll
                for (int q = 0; q < 4; ++q) {
                    acc[q][r] = fmaf(w4[q].x, x4.x, acc[q][r]);
                    acc[q][r] = fmaf(w4[q].y, x4.y, acc[q][r]);
                    acc[q][r] = fmaf(w4[q].z, x4.z, acc[q][r]);
                    acc[q][r] = fmaf(w4[q].w, x4.w, acc[q][r]);
                }
            }
        }
        // reduce over eq (lanes xor 1,2,4,8 inside 16-lane groups)
#pragma unroll
        for (int q = 0; q < 4; ++q)
#pragma unroll
            for (int r = 0; r < RB; ++r) {
                float v = acc[q][r];
                v += __shfl_xor(v, 1);
                v += __shfl_xor(v, 2);
                v += __shfl_xor(v, 4);
                v += __shfl_xor(v, 8);
                acc[q][r] = v;
            }
        if (eq == 0) {
#pragma unroll
            for (int q = 0; q < 4; ++q) {
                const int p = pg + q * 16;
                const float bb = dp_b[p];
#pragma unroll
                for (int r = 0; r < RB; ++r) {
                    const float h = acc[q][r] + bb;
                    muL[r][p] = h / (1.f + __expf(-h));   // swish
                }
            }
        }
    }
    __syncthreads();

    // Phase 3: V[row][h][j] = mu[row][:] @ W1[j][:][h] + B1[j][h].
    // wave = h-quad (h0 = wave*4), lane = j.
    {
        const int h0 = wave * 4;
        const int j = lane;
        float4 acc[RB];
        const float4 b4 = *reinterpret_cast<const float4*>(B1 + j * C + h0);
#pragma unroll
        for (int r = 0; r < RB; ++r) acc[r] = b4;
        const float* w1p = W1 + (size_t)j * P * C + h0;   // W1[j][d][h]
        for (int d = 0; d < P; ++d) {
            const float4 w4 = *reinterpret_cast<const float4*>(w1p + (size_t)d * C);
#pragma unroll
            for (int r = 0; r < RB; ++r) {
                const float m = muL[r][d];
                acc[r].x = fmaf(m, w4.x, acc[r].x);
                acc[r].y = fmaf(m, w4.y, acc[r].y);
                acc[r].z = fmaf(m, w4.z, acc[r].z);
                acc[r].w = fmaf(m, w4.w, acc[r].w);
            }
        }
#pragma unroll
        for (int r = 0; r < RB; ++r) {
            const size_t row = (size_t)(row0 + r);
            float* vp = V + (row * C + h0) * (size_t)P + j;
            vp[0 * P] = acc[r].x;
            vp[1 * P] = acc[r].y;
            vp[2 * P] = acc[r].z;
            vp[3 * P] = acc[r].w;
        }
    }
}

// ---------------------------------------------------------------------------
// K2: one routing-1 iteration pass over V (layout [row][h][j]). Block =
// (b, tile of 64 i); lane = j. Coalesced loads, double-buffered across s.
// E-step quad form expanded: sc = c0 + sum_h va*(c1 - va*iv).
__global__ __launch_bounds__(256) void
k2_pass(const float* __restrict__ V, const float* __restrict__ mask,
        const float* __restrict__ c1v, const float* __restrict__ ivv,
        const float* __restrict__ c0v, float* __restrict__ Smu,
        float* __restrict__ SV2, float* __restrict__ Dsum, const int it)
{
    __shared__ float lacc[P][34];   // [j][0..15]=Smu, [16..31]=SV2, [32]=Dsum
    const int tid = threadIdx.x;
    const int wave = tid >> 6, j = tid & 63;
    const int b = blockIdx.x / (NI / 64);
    const int tile = blockIdx.x % (NI / 64);

    for (int k = tid; k < P * 34; k += 256) (&lacc[0][0])[k] = 0.f;

    float c1[16], iv[16], c0 = 0.f;
    if (it > 0) {
        const float4* cp = reinterpret_cast<const float4*>(c1v + ((size_t)b * P + j) * C);
        const float4* ip = reinterpret_cast<const float4*>(ivv + ((size_t)b * P + j) * C);
#pragma unroll
        for (int k = 0; k < 4; ++k) {
            const float4 c4 = cp[k]; const float4 i4 = ip[k];
            c1[k * 4 + 0] = c4.x; c1[k * 4 + 1] = c4.y; c1[k * 4 + 2] = c4.z; c1[k * 4 + 3] = c4.w;
            iv[k * 4 + 0] = i4.x; iv[k * 4 + 1] = i4.y; iv[k * 4 + 2] = i4.z; iv[k * 4 + 3] = i4.w;
        }
        c0 = c0v[(size_t)b * P + j];
    }

    const int i0 = tile * 64 + wave * 16;
    const float* vb = V + ((size_t)(b * NI + i0) * C) * P + j;

    float dsum = 0.f;
    float smuA[16], sv2A[16];
#pragma unroll
    for (int h = 0; h < 16; ++h) { smuA[h] = 0.f; sv2A[h] = 0.f; }

    __syncthreads();

    float va[2][16];
#pragma unroll
    for (int h = 0; h < 16; ++h) va[0][h] = vb[(size_t)h * P];

#pragma unroll
    for (int s = 0; s < 16; ++s) {
        const int cb = s & 1;
        if (s < 15) {
#pragma unroll
            for (int h = 0; h < 16; ++h)
                va[cb ^ 1][h] = vb[(size_t)((s + 1) * C + h) * P];
        }
        float R;
        if (it > 0) {
            float q = c0;
#pragma unroll
            for (int h = 0; h < 16; ++h) {
                const float v = va[cb][h];
                q = fmaf(v, fmaf(-v, iv[h], c1[h]), q);
            }
            float m = q;
#pragma unroll
            for (int off = 32; off > 0; off >>= 1) m = fmaxf(m, __shfl_xor(m, off));
            const float e = __expf(q - m);
            float sum = e;
#pragma unroll
            for (int off = 32; off > 0; off >>= 1) sum += __shfl_xor(sum, off);
            R = e / sum;
        } else {
            R = 1.f / 64.f;
        }
        const int i = i0 + s;
        const float fa = mask[b * TT + i / DD];   // fa = sigmoid(logit(mask)) = mask
        const float w = fa * R;
        dsum += w;
#pragma unroll
        for (int h = 0; h < 16; ++h) {
            const float v = va[cb][h];
            smuA[h] = fmaf(w, v, smuA[h]);
            sv2A[h] = fmaf(w * v, v, sv2A[h]);
        }
    }

#pragma unroll
    for (int h = 0; h < 16; ++h) {
        atomicAdd(&lacc[j][h], smuA[h]);
        atomicAdd(&lacc[j][16 + h], sv2A[h]);
    }
    atomicAdd(&lacc[j][32], dsum);
    __syncthreads();

    for (int k = tid; k < P * 33; k += 256) {
        const int jj = k / 33, r = k % 33;
        const float v = lacc[jj][r];
        if (r < 16)      atomicAdd(&Smu[((size_t)b * P + jj) * C + r], v);
        else if (r < 32) atomicAdd(&SV2[((size_t)b * P + jj) * C + (r - 16)], v);
        else             atomicAdd(&Dsum[(size_t)b * P + jj], v);
    }
}

// ---------------------------------------------------------------------------
// K2f: finalize one routing-1 iteration. Produces mu_out plus the E-step
// constants: iv = 1/(2 sig2), c1 = 2*mu*iv, c0 = logsig(a) - 0.5*sum log sig2
// - sum mu^2*iv. One thread per (b,j).
__global__ void k2f(const float* __restrict__ Smu, const float* __restrict__ SV2,
                    const float* __restrict__ Dsum, const float* __restrict__ sumfa,
                    const float* __restrict__ bu, const float* __restrict__ bi,
                    float* __restrict__ muo, float* __restrict__ ivv,
                    float* __restrict__ c1v, float* __restrict__ c0v,
                    float* __restrict__ a1)
{
    const int t = blockIdx.x * blockDim.x + threadIdx.x;
    if (t >= BQ * P) return;
    const int b = t / P, j = t % P;
    const float ds = Dsum[t];
    const float inv = 1.f / ds;
    const float ao = bu[j] * ds - bi[j] * (sumfa[b] - ds);
    a1[t] = ao;
    const float lsg = (ao < 0.f) ? (ao - log1pf(__expf(ao))) : (-log1pf(__expf(-ao)));
    float sumlog = 0.f, moiv = 0.f;
#pragma unroll
    for (int h = 0; h < C; ++h) {
        const float m = Smu[t * C + h] * inv;
        const float s2 = fmaxf(SV2[t * C + h] * inv - m * m, 0.f) + 1e-5f;
        const float iv = 0.5f / s2;
        muo[t * C + h] = m;
        ivv[t * C + h] = iv;
        c1v[t * C + h] = 2.f * m * iv;
        sumlog += logf(s2);
        moiv += m * m * iv;
    }
    c0v[t] = lsg - 0.5f * sumlog - moiv;
}

// ---------------------------------------------------------------------------
// K3: routing 2 (n_i=64, n_o=5, d=16) entirely inside one block per batch.
__global__ void k3_routing2(const float* __restrict__ muo, const float* __restrict__ a1,
                            const float* __restrict__ W2, const float* __restrict__ B2,
                            const float* __restrict__ bu2, const float* __restrict__ bi2,
                            float* __restrict__ out)
{
    __shared__ float mu1L[P][C];
    __shared__ float faL[P];
    __shared__ float V2L[P][NC][C];
    __shared__ float RL[P][NC];
    __shared__ float mu2L[NC][C];
    __shared__ float s2L[NC][C];
    __shared__ float isL[NC][C];
    __shared__ float dsL[NC];
    __shared__ float biasL[NC];
    __shared__ float a2L[NC];
    __shared__ float sumfa2s;
    const int b = blockIdx.x, tid = threadIdx.x;

    for (int k = tid; k < P * C; k += 256) (&mu1L[0][0])[k] = muo[(size_t)b * P * C + k];
    if (tid < P) {
        const float a = a1[(size_t)b * P + tid];
        faL[tid] = 1.f / (1.f + __expf(-a));
    }
    __syncthreads();
    if (tid == 0) {
        float s = 0.f;
        for (int i = 0; i < P; ++i) s += faL[i];
        sumfa2s = s;
    }
    // V2[i][j][h] = mu1[i][:] @ W2[i][j][:][h] + B2[j][h]
    {
        const int i = tid >> 2, hq = tid & 3;
        for (int jj = 0; jj < NC; ++jj) {
            float4 acc = *reinterpret_cast<const float4*>(B2 + jj * C + hq * 4);
            const float* wp = W2 + ((size_t)(i * NC + jj) * C) * C + hq * 4;
#pragma unroll
            for (int d = 0; d < C; ++d) {
                const float m = mu1L[i][d];
                const float4 w4 = *reinterpret_cast<const float4*>(wp + d * C);
                acc.x += m * w4.x; acc.y += m * w4.y; acc.z += m * w4.z; acc.w += m * w4.w;
            }
            *reinterpret_cast<float4*>(&V2L[i][jj][hq * 4]) = acc;
        }
    }
    __syncthreads();

    for (int it = 0; it < 3; ++it) {
        if (tid < P) {
            const int i = tid;
            if (it == 0) {
#pragma unroll
                for (int jj = 0; jj < NC; ++jj) RL[i][jj] = 1.f / NC;
            } else {
                float sc[NC];
                float m = -3.4e38f;
#pragma unroll
                for (int jj = 0; jj < NC; ++jj) {
                    float q = 0.f;
#pragma unroll
                    for (int h = 0; h < C; ++h) {
                        const float d = V2L[i][jj][h] - mu2L[jj][h];
                        q += d * d * isL[jj][h];
                    }
                    sc[jj] = biasL[jj] - q;
                    m = fmaxf(m, sc[jj]);
                }
                float sum = 0.f;
#pragma unroll
                for (int jj = 0; jj < NC; ++jj) { sc[jj] = __expf(sc[jj] - m); sum += sc[jj]; }
                const float invs = 1.f / sum;
#pragma unroll
                for (int jj = 0; jj < NC; ++jj) RL[i][jj] = sc[jj] * invs;
            }
        }
        __syncthreads();
        if (tid < NC) {
            float ds = 0.f;
            for (int i = 0; i < P; ++i) ds += faL[i] * RL[i][tid];
            dsL[tid] = ds;
        }
        __syncthreads();
        if (tid < NC * C) {
            const int jj = tid / C, h = tid % C;
            float smu = 0.f, sv2 = 0.f;
            for (int i = 0; i < P; ++i) {
                const float w = faL[i] * RL[i][jj];
                const float v = V2L[i][jj][h];
                smu += w * v;
                sv2 += w * v * v;
            }
            const float inv = 1.f / dsL[jj];
            const float m = smu * inv;
            const float s2 = fmaxf(sv2 * inv - m * m, 0.f) + 1e-5f;
            mu2L[jj][h] = m;
            s2L[jj][h] = s2;
            isL[jj][h] = 0.5f / s2;
        }
        __syncthreads();
        if (tid < NC) {
            const float ds = dsL[tid];
            const float ao = bu2[tid] * ds - bi2[tid] * (sumfa2s - ds);
            a2L[tid] = ao;
            const float lsg = (ao < 0.f) ? (ao - log1pf(__expf(ao))) : (-log1pf(__expf(-ao)));
            float sl = 0.f;
#pragma unroll
            for (int h = 0; h < C; ++h) sl += logf(s2L[tid][h]);
            biasL[tid] = lsg - 0.5f * sl;
        }
        __syncthreads();
    }

    // outputs: a [32,5] | mu [32,5,1,16] | sig2 [32,5,1,16]
    if (tid < NC) out[(size_t)b * NC + tid] = a2L[tid];
    if (tid < NC * C) {
        const int jj = tid / C, h = tid % C;
        out[BQ * NC + ((size_t)b * NC + jj) * C + h] = mu2L[jj][h];
        out[BQ * NC + BQ * NC * C + ((size_t)b * NC + jj) * C + h] = s2L[jj][h];
    }
}

// ---------------------------------------------------------------------------
extern "C" void kernel_launch(void* const* d_in, const int* in_sizes, int n_in,
                              void* d_out, int out_size, void* d_ws, size_t ws_size,
                              hipStream_t stream)
{
    (void)in_sizes; (void)n_in; (void)out_size; (void)ws_size;
    const float* mask      = (const float*)d_in[0];
    const float* embs      = (const float*)d_in[1];
    const float* depth_emb = (const float*)d_in[2];
    const float* ln_w      = (const float*)d_in[3];
    const float* ln_b      = (const float*)d_in[4];
    const float* dp_w      = (const float*)d_in[5];
    const float* dp_b      = (const float*)d_in[6];
    const float* W1        = (const float*)d_in[7];
    const float* B1        = (const float*)d_in[8];
    const float* bu1       = (const float*)d_in[9];
    const float* bi1       = (const float*)d_in[10];
    const float* W2        = (const float*)d_in[11];
    const float* B2        = (const float*)d_in[12];
    const float* bu2       = (const float*)d_in[13];
    const float* bi2       = (const float*)d_in[14];
    float* out = (float*)d_out;

    // workspace layout (floats). Needs ~219 MB.
    float* ws = (float*)d_ws;
    size_t o = 0;
    float* V     = ws + o; o += (size_t)NROWS * P * C;   // 54,525,952
    float* Smu   = ws + o; o += (size_t)BQ * P * C;      // contiguous with SV2, Dsum (one memset)
    float* SV2   = ws + o; o += (size_t)BQ * P * C;
    float* Dsum  = ws + o; o += (size_t)BQ * P;
    float* muo   = ws + o; o += (size_t)BQ * P * C;
    float* ivv   = ws + o; o += (size_t)BQ * P * C;
    float* c1v   = ws + o; o += (size_t)BQ * P * C;
    float* c0v   = ws + o; o += (size_t)BQ * P;
    float* a1    = ws + o; o += (size_t)BQ * P;
    float* sumfa = ws + o; o += (size_t)BQ;

    k_sumfa<<<BQ, 128, 0, stream>>>(mask, sumfa);
    k1_parts_v<<<NROWS / RB, 256, 0, stream>>>(embs, depth_emb, ln_w, ln_b,
                                               dp_w, dp_b, W1, B1, V);
    for (int it = 0; it < 3; ++it) {
        hipMemsetAsync(Smu, 0, (size_t)(2 * BQ * P * C + BQ * P) * sizeof(float), stream);
        k2_pass<<<BQ * (NI / 64), 256, 0, stream>>>(V, mask, c1v, ivv, c0v,
                                                    Smu, SV2, Dsum, it);
        k2f<<<(BQ * P) / 256, 256, 0, stream>>>(Smu, SV2, Dsum, sumfa, bu1, bi1,
                                                muo, ivv, c1v, c0v, a1);
    }
    k3_routing2<<<BQ, 256, 0, stream>>>(muo, a1, W2, B2, bu2, bi2, out);
}